// Round 10
// baseline (164.032 us; speedup 1.0000x reference)
//
#include <hip/hip_runtime.h>
#include <math.h>

#define B_   16
#define SQ_  1024
#define SC_  1024
#define D_   768
#define H_   1536
#define BK   32   // k-tile
#define LDK  40   // padded LDS leading dim (bf16 elems) for k-tiles of 32

typedef __attribute__((ext_vector_type(4))) float f32x4;
typedef __attribute__((ext_vector_type(8))) short bf16x8;

// packed f32x2 -> bf16x2 (RNE), low16 = bf16(x), high16 = bf16(y)
__device__ __forceinline__ unsigned cvtpk(float x, float y) {
  unsigned r;
  asm("v_cvt_pk_bf16_f32 %0, %1, %2" : "=v"(r) : "v"(x), "v"(y));
  return r;
}

// split float4 -> (hi bf16x4, lo bf16x4); lo = x - hi exactly representable
__device__ __forceinline__ void split4(float4 v, uint2& hi, uint2& lo) {
  unsigned h01 = cvtpk(v.x, v.y);
  unsigned h23 = cvtpk(v.z, v.w);
  float h0 = __uint_as_float(h01 << 16);
  float h1 = __uint_as_float(h01 & 0xFFFF0000u);
  float h2 = __uint_as_float(h23 << 16);
  float h3 = __uint_as_float(h23 & 0xFFFF0000u);
  hi = make_uint2(h01, h23);
  lo = make_uint2(cvtpk(v.x - h0, v.y - h1), cvtpk(v.z - h2, v.w - h3));
}

// e^s as a double, for s in ~[-200, 200]: 2^frac via exp2f, 2^int via exponent bits
__device__ __forceinline__ double exp_pos(float s) {
  float t = s * 1.4426950408889634f;   // s * log2(e)
  float n = floorf(t);
  float p = exp2f(t - n);              // 2^frac in [1,2)
  long long e = (long long)n;
  double scale = __longlong_as_double((unsigned long long)(e + 1023LL) << 52);
  return (double)p * scale;
}

// ---------------------------------------------------------------------------
// Kernel 0: per (batch, which) mask compaction. Stable prefix-sum scan.
// ---------------------------------------------------------------------------
__global__ __launch_bounds__(256) void compact_kernel(
    const int* __restrict__ mask_q, const int* __restrict__ mask_c,
    int* __restrict__ idx_q, int* __restrict__ idx_c, int* __restrict__ cnt)
{
  int which = blockIdx.x & 1;   // 0: q, 1: c
  int b     = blockIdx.x >> 1;
  const int* m = (which ? mask_c : mask_q) + b * 1024;
  int* idx     = (which ? idx_c : idx_q) + b * 1024;

  __shared__ int tsum[256];
  int t = threadIdx.x;
  int v[4], s = 0;
#pragma unroll
  for (int e = 0; e < 4; ++e) { v[e] = (m[t * 4 + e] != 0) ? 1 : 0; s += v[e]; }
  tsum[t] = s;
  __syncthreads();
  for (int off = 1; off < 256; off <<= 1) {
    int add = (t >= off) ? tsum[t - off] : 0;
    __syncthreads();
    tsum[t] += add;
    __syncthreads();
  }
  int pos = tsum[t] - s;   // exclusive prefix
#pragma unroll
  for (int e = 0; e < 4; ++e) {
    if (v[e]) idx[pos++] = t * 4 + e;
  }
  if (t == 255) cnt[b * 2 + which] = tsum[255];
}

// ---------------------------------------------------------------------------
// Kernel 0b: tile bookkeeping for the persistent GEMM.
// tmeta[0]=total tiles, [1+b]=tile offset of batch b, [17+b]=ntc_b, [33]=ctr=0
// ---------------------------------------------------------------------------
__global__ void tile_setup_kernel(const int* __restrict__ cnt, int* __restrict__ tmeta)
{
  if (threadIdx.x == 0) {
    int off = 0;
    for (int b = 0; b < B_; ++b) {
      int ntq = (cnt[2 * b] + 63) >> 6;
      int ntc = (cnt[2 * b + 1] + 63) >> 6;
      tmeta[1 + b]  = off;
      tmeta[17 + b] = ntc;
      off += ntq * ntc;
    }
    tmeta[0]  = off;
    tmeta[33] = 0;
  }
}

// ---------------------------------------------------------------------------
// Kernel 1: PERSISTENT compact GEMM. 1024 blocks pull 64x64 tiles from a
// work queue. Split-bf16 MFMA, double-buffered LDS, BK=32. Epilogue writes
// S (fp32, -inf coded) AND accumulates exp-domain row/col sums R,C (double)
// via shfl/LDS reduction + atomics.
// ---------------------------------------------------------------------------
__global__ __launch_bounds__(256) void gemm_mfma_kernel(
    const float* __restrict__ q, const float* __restrict__ c,
    const int* __restrict__ idx_q, const int* __restrict__ idx_c,
    const int* __restrict__ cnt, int* __restrict__ tmeta,
    float* __restrict__ S, double* __restrict__ R, double* __restrict__ C)
{
  __shared__ unsigned short Ah[2][64][LDK];
  __shared__ unsigned short Al[2][64][LDK];
  __shared__ unsigned short Bh[2][64][LDK];
  __shared__ unsigned short Bl[2][64][LDK];   // 40960 B
  __shared__ int tidx_s;

  const int t    = threadIdx.x;
  const int lane = t & 63;
  const int w    = t >> 6;            // 0..3 = n-frag
  const int srow = t >> 2;            // 0..63 staging row
  const int kc   = (t & 3) * 4;       // k sub-offset; covers kc and kc+16
  const int fr   = lane & 15;
  const int fq   = lane >> 4;
  const int kg   = fq * 8;

  const int total = tmeta[0];

  while (true) {
    if (t == 0) tidx_s = atomicAdd(&tmeta[33], 1);
    __syncthreads();
    const int idx = tidx_s;
    if (idx >= total) break;

    // decode tile -> (b, ty, tx)
    int bb = 0;
#pragma unroll
    for (int k = 1; k < 16; ++k) bb += (idx >= tmeta[1 + k]) ? 1 : 0;
    const int rem = idx - tmeta[1 + bb];
    const int ntc = tmeta[17 + bb];
    const int ty  = rem / ntc;
    const int tx  = rem - ty * ntc;
    const int i0  = ty * 64, j0 = tx * 64;
    const int nq  = cnt[2 * bb], nc = cnt[2 * bb + 1];

    const int rq = idx_q[bb * 1024 + min(i0 + srow, nq - 1)];
    const int rc = idx_c[bb * 1024 + min(j0 + srow, nc - 1)];
    const float* qrowP = q + ((size_t)bb * SQ_ + rq) * D_;
    const float* crowP = c + ((size_t)bb * SC_ + rc) * D_;

    f32x4 acc[4] = {};

    // prologue: k-tile 0 -> buf 0
    float4 av0 = *(const float4*)(qrowP + kc);
    float4 av1 = *(const float4*)(qrowP + kc + 16);
    float4 bv0 = *(const float4*)(crowP + kc);
    float4 bv1 = *(const float4*)(crowP + kc + 16);
    {
      uint2 hi, lo;
      split4(av0, hi, lo); *(uint2*)&Ah[0][srow][kc]      = hi; *(uint2*)&Al[0][srow][kc]      = lo;
      split4(av1, hi, lo); *(uint2*)&Ah[0][srow][kc + 16] = hi; *(uint2*)&Al[0][srow][kc + 16] = lo;
      split4(bv0, hi, lo); *(uint2*)&Bh[0][srow][kc]      = hi; *(uint2*)&Bl[0][srow][kc]      = lo;
      split4(bv1, hi, lo); *(uint2*)&Bh[0][srow][kc + 16] = hi; *(uint2*)&Bl[0][srow][kc + 16] = lo;
    }
    __syncthreads();

    int cur = 0;
    for (int k0 = 0; k0 < D_; k0 += BK) {
      const int next = k0 + BK;
      const bool has_next = (next < D_);
      if (has_next) {
        av0 = *(const float4*)(qrowP + next + kc);
        av1 = *(const float4*)(qrowP + next + kc + 16);
        bv0 = *(const float4*)(crowP + next + kc);
        bv1 = *(const float4*)(crowP + next + kc + 16);
      }

      bf16x8 b_h = *reinterpret_cast<const bf16x8*>(&Bh[cur][w * 16 + fr][kg]);
      bf16x8 b_l = *reinterpret_cast<const bf16x8*>(&Bl[cur][w * 16 + fr][kg]);
#pragma unroll
      for (int m = 0; m < 4; ++m) {
        bf16x8 a_h = *reinterpret_cast<const bf16x8*>(&Ah[cur][m * 16 + fr][kg]);
        bf16x8 a_l = *reinterpret_cast<const bf16x8*>(&Al[cur][m * 16 + fr][kg]);
        acc[m] = __builtin_amdgcn_mfma_f32_16x16x32_bf16(a_h, b_h, acc[m], 0, 0, 0);
        acc[m] = __builtin_amdgcn_mfma_f32_16x16x32_bf16(a_h, b_l, acc[m], 0, 0, 0);
        acc[m] = __builtin_amdgcn_mfma_f32_16x16x32_bf16(a_l, b_h, acc[m], 0, 0, 0);
      }

      if (has_next) {
        int nxt = cur ^ 1;
        uint2 hi, lo;
        split4(av0, hi, lo); *(uint2*)&Ah[nxt][srow][kc]      = hi; *(uint2*)&Al[nxt][srow][kc]      = lo;
        split4(av1, hi, lo); *(uint2*)&Ah[nxt][srow][kc + 16] = hi; *(uint2*)&Al[nxt][srow][kc + 16] = lo;
        split4(bv0, hi, lo); *(uint2*)&Bh[nxt][srow][kc]      = hi; *(uint2*)&Bl[nxt][srow][kc]      = lo;
        split4(bv1, hi, lo); *(uint2*)&Bh[nxt][srow][kc + 16] = hi; *(uint2*)&Bl[nxt][srow][kc + 16] = lo;
      }
      __syncthreads();
      cur ^= 1;
    }

    // ---- epilogue: S store + exp-domain R/C accumulation ----
    double* rowAcc = reinterpret_cast<double*>(&Ah[0][0][0]);  // 256 doubles, LDS reuse
    const int col = j0 + w * 16 + fr;
    const bool cok = (col < nc);
    double colSum = 0.0;
#pragma unroll
    for (int m = 0; m < 4; ++m) {
      int rbase = i0 + m * 16 + fq * 4;
      float* Sp = S + ((size_t)bb * SQ_ + rbase) * SC_ + col;
#pragma unroll
      for (int rr = 0; rr < 4; ++rr) {
        float v = acc[m][rr];
        bool valid = ((rbase + rr) < nq) && cok && (v != 0.f);
        Sp[(size_t)rr * SC_] = valid ? v : -INFINITY;
        double e = valid ? exp_pos(v) : 0.0;
        colSum += e;
        double rsum = e;
        rsum += __shfl_xor(rsum, 1);
        rsum += __shfl_xor(rsum, 2);
        rsum += __shfl_xor(rsum, 4);
        rsum += __shfl_xor(rsum, 8);
        if (fr == 0) rowAcc[w * 64 + m * 16 + fq * 4 + rr] = rsum;
      }
    }
    colSum += __shfl_xor(colSum, 16);
    colSum += __shfl_xor(colSum, 32);
    if (fq == 0 && cok) atomicAdd(&C[bb * SC_ + col], colSum);
    __syncthreads();
    if (t < 64) {
      double rs = rowAcc[t] + rowAcc[64 + t] + rowAcc[128 + t] + rowAcc[192 + t];
      if ((i0 + t) < nq && rs != 0.0) atomicAdd(&R[bb * SQ_ + i0 + t], rs);
    }
    __syncthreads();   // rowAcc consumed before next tile's prologue/tidx_s
  }
}

// ---------------------------------------------------------------------------
// Kernel 2: single pass over S -> cp[j] = sum_i e^{s-lnR_i} and
// rpp[i] = sum_j e^{s-lnC_j}. 64-col strip per block, 16 waves over rows.
// Dead rows/cols encoded lnX = +inf (=> exp -> 0, and -inf - inf = -inf).
// ---------------------------------------------------------------------------
__global__ __launch_bounds__(1024) void pass2_kernel(
    const float* __restrict__ S, const int* __restrict__ cnt,
    const double* __restrict__ R, const double* __restrict__ C,
    float* __restrict__ cp, float* __restrict__ rpp)
{
  __shared__ float lnR_lds[SQ_];
  __shared__ float red[16][64];

  int b  = blockIdx.y;
  int j0 = blockIdx.x * 64;
  int nq_pad = (cnt[2 * b] + 63) & ~63;
  int nc_pad = (cnt[2 * b + 1] + 63) & ~63;
  if (j0 >= nc_pad) return;        // block-uniform exit before barriers
  int t = threadIdx.x;

  if (t < nq_pad) {
    double Ri = R[b * SQ_ + t];
    lnR_lds[t] = (Ri > 0.0) ? (float)log(Ri) : INFINITY;
  }
  __syncthreads();

  int lane = t & 63, wv = t >> 6;
  int j = j0 + lane;
  double Cj = C[b * SC_ + j];
  float lnCj = (Cj > 0.0) ? (float)log(Cj) : INFINITY;

  int chunk = nq_pad >> 4;          // rows per wave
  int i0 = wv * chunk;
  const float* Sb = S + ((size_t)b * SQ_ + i0) * SC_ + j;

  float cpAcc = 0.f;
  for (int ii = 0; ii < chunk; ++ii) {
    int i = i0 + ii;
    float v = Sb[(size_t)ii * SC_];
    cpAcc += __expf(v - lnR_lds[i]);
    float e2 = __expf(v - lnCj);
#pragma unroll
    for (int o = 32; o; o >>= 1) e2 += __shfl_xor(e2, o);
    if (lane == 0) atomicAdd(&rpp[b * SQ_ + i], e2);
  }

  red[wv][lane] = cpAcc;
  __syncthreads();
  if (t < 64) {
    float s = 0.f;
#pragma unroll
    for (int k = 0; k < 16; ++k) s += red[k][t];
    cp[b * SC_ + j0 + t] = s;
  }
}

// ---------------------------------------------------------------------------
// Kernel 5: combine partials over VALID rows via idx gather; atomicAdd into X.
// ---------------------------------------------------------------------------
__global__ __launch_bounds__(256) void combine_kernel(
    const float* __restrict__ q, const float* __restrict__ c,
    const int* __restrict__ idx_q, const int* __restrict__ idx_c,
    const int* __restrict__ cnt,
    const float* __restrict__ cp, const float* __restrict__ rpp,
    float* __restrict__ X)
{
  int jc = blockIdx.x;   // 0..31
  int op = blockIdx.y;   // 0: c/cp ; 1: q/rpp
  int b  = blockIdx.z;
  int t  = threadIdx.x;

  int n = op ? cnt[2 * b] : cnt[2 * b + 1];
  const float* src = op ? (q + (size_t)b * SQ_ * D_) : (c + (size_t)b * SC_ * D_);
  const float* wv  = op ? (rpp + b * SQ_) : (cp + b * SC_);
  const int*   idx = (op ? idx_q : idx_c) + b * 1024;

  float a0 = 0.f, a1 = 0.f, a2 = 0.f;
  int je = min(jc * 32 + 32, n);
  for (int j = jc * 32; j < je; ++j) {
    float wj = wv[j];
    const float* r = src + (size_t)idx[j] * D_;
    a0 += wj * r[t];
    a1 += wj * r[t + 256];
    a2 += wj * r[t + 512];
  }
  float* xp = X + (size_t)b * H_ + op * D_;
  atomicAdd(&xp[t], a0);
  atomicAdd(&xp[t + 256], a1);
  atomicAdd(&xp[t + 512], a2);
}

// ---------------------------------------------------------------------------
// Kernel 7: fc1. One wave per h; W1 row in registers, loop over 16 batches.
// ---------------------------------------------------------------------------
__global__ __launch_bounds__(256) void fc1_kernel(
    const float* __restrict__ X, const float* __restrict__ W1,
    const float* __restrict__ b1, float* __restrict__ Y)
{
  int w = threadIdx.x >> 6, lane = threadIdx.x & 63;
  int h = blockIdx.x * 4 + w;           // 0..1535
  const float4* wr = (const float4*)(W1 + (size_t)h * H_);
  float4 wv[6];
#pragma unroll
  for (int it = 0; it < 6; ++it) wv[it] = wr[it * 64 + lane];
  float bias = b1[h];

  for (int b = 0; b < B_; ++b) {
    const float4* x = (const float4*)(X + (size_t)b * H_);
    float accv = 0.f;
#pragma unroll
    for (int it = 0; it < 6; ++it) {
      float4 xv = x[it * 64 + lane];
      accv += xv.x * wv[it].x + xv.y * wv[it].y + xv.z * wv[it].z + xv.w * wv[it].w;
    }
#pragma unroll
    for (int o = 32; o; o >>= 1) accv += __shfl_xor(accv, o);
    if (lane == 0) Y[(size_t)b * H_ + h] = tanhf(accv + bias);
  }
}

// ---------------------------------------------------------------------------
// Kernel 8: fc2 + log_softmax + NLL loss.
// ---------------------------------------------------------------------------
__global__ __launch_bounds__(64) void fc2_loss_kernel(
    const float* __restrict__ Y, const float* __restrict__ W2,
    const float* __restrict__ b2, const int* __restrict__ labels,
    float* __restrict__ out)
{
  __shared__ float logp_s[B_][2];
  int t = threadIdx.x;
  if (t < 2 * B_) {
    int b = t >> 1, n = t & 1;
    const float* y = Y + (size_t)b * H_;
    const float* w = W2 + (size_t)n * H_;
    float accv = b2[n];
    for (int k = 0; k < H_; ++k) accv += y[k] * w[k];
    logp_s[b][n] = accv;
  }
  __syncthreads();
  if (t < B_) {
    float l0 = logp_s[t][0], l1 = logp_s[t][1];
    float m = fmaxf(l0, l1);
    float lse = m + logf(expf(l0 - m) + expf(l1 - m));
    logp_s[t][0] = l0 - lse;
    logp_s[t][1] = l1 - lse;
  }
  __syncthreads();
  if (t < 2 * B_) out[1 + t] = logp_s[t >> 1][t & 1];
  if (t == 0) {
    float loss = 0.f;
    for (int b = 0; b < B_; ++b) loss -= logp_s[b][labels[b]];
    out[0] = loss / (float)B_;
  }
}

// ---------------------------------------------------------------------------
extern "C" void kernel_launch(void* const* d_in, const int* in_sizes, int n_in,
                              void* d_out, int out_size, void* d_ws, size_t ws_size,
                              hipStream_t stream) {
  const float* q      = (const float*)d_in[0];
  const float* c      = (const float*)d_in[1];
  const int*   mask_q = (const int*)d_in[2];
  const int*   mask_c = (const int*)d_in[3];
  const int*   labels = (const int*)d_in[4];
  const float* W1     = (const float*)d_in[5];
  const float* b1     = (const float*)d_in[6];
  const float* W2     = (const float*)d_in[7];
  const float* b2     = (const float*)d_in[8];
  float* out = (float*)d_out;

  float*  ws   = (float*)d_ws;
  float*  S    = ws;                                  // 16M floats (64 MiB)
  double* R    = (double*)(ws + (size_t)B_ * SQ_ * SC_); // 16K doubles
  double* C    = R + B_ * SQ_;                        // 16K doubles
  float*  cp   = (float*)(C + B_ * SC_);              // 16K floats
  float*  rpp  = cp + B_ * SC_;                       // 16K floats
  int*    cnt  = (int*)(rpp + B_ * SQ_);              // 32 ints
  int*    tmeta = cnt + 2 * B_;                       // 34 ints
  int*    idx_q = tmeta + 34;
  int*    idx_c = idx_q + B_ * SQ_;
  // X/Y overlay S (S dead after pass2)
  float*  X    = ws;                                  // 16*1536
  float*  Y    = ws + B_ * H_;                        // 16*1536

  // zero R, C, cp, rpp in one contiguous memset (384 KB)
  (void)hipMemsetAsync((void*)R, 0, (size_t)(2 * B_ * SQ_) * sizeof(double)
                              + (size_t)(2 * B_ * SC_) * sizeof(float), stream);

  compact_kernel<<<2 * B_, 256, 0, stream>>>(mask_q, mask_c, idx_q, idx_c, cnt);
  tile_setup_kernel<<<1, 64, 0, stream>>>(cnt, tmeta);

  gemm_mfma_kernel<<<1024, 256, 0, stream>>>(q, c, idx_q, idx_c, cnt, tmeta, S, R, C);

  pass2_kernel<<<dim3(SC_ / 64, B_), 1024, 0, stream>>>(S, cnt, R, C, cp, rpp);

  (void)hipMemsetAsync((void*)X, 0, (size_t)B_ * H_ * sizeof(float), stream);
  combine_kernel<<<dim3(32, 2, B_), 256, 0, stream>>>(q, c, idx_q, idx_c, cnt,
                                                      cp, rpp, X);
  fc1_kernel<<<H_ / 4, 256, 0, stream>>>(X, W1, b1, Y);
  fc2_loss_kernel<<<1, 64, 0, stream>>>(Y, W2, b2, labels, out);
}